// Round 1
// baseline (122.714 us; speedup 1.0000x reference)
//
#include <hip/hip_runtime.h>

// STGraphConstructor: adj[b] = tanh(relu(A_b A_b^T) + I), A_b = [5096 x 64] fp32
// (concat of spatial [5000x64] and temporal [96x64]).
// Strategy: split-bf16 (hi+lo) x3 MFMA products for fp32-grade accuracy at
// bf16 MFMA rate; 128x128 output tile / block; XOR-swizzled LDS; fast tanh.

#define NSP 5000
#define NTM 96
#define MM  5096
#define DD  64
#define BT  128
#define NTILE 40   // ceil(5096/128)

typedef __attribute__((ext_vector_type(8))) short short8;
typedef __attribute__((ext_vector_type(8))) unsigned short ushort8;
typedef __attribute__((ext_vector_type(4))) float f32x4;

// LDS: 4 arrays of [128 rows][64 bf16] = 16 KB each
#define OFF_RH 0u
#define OFF_RL 16384u
#define OFF_CH 32768u
#define OFF_CL 49152u

__device__ __forceinline__ unsigned short bf16_rn(float x) {
  unsigned u = __float_as_uint(x);
  u += 0x7FFFu + ((u >> 16) & 1u);
  return (unsigned short)(u >> 16);
}
__device__ __forceinline__ float bf16_f32(unsigned short s) {
  return __uint_as_float(((unsigned)s) << 16);
}

__global__ __launch_bounds__(256) void stg_adj_kernel(
    const float* __restrict__ sp, const float* __restrict__ tm,
    float* __restrict__ out) {
  __shared__ unsigned char lds[65536];
  const int bi = blockIdx.x;   // output row tile
  const int bj = blockIdx.y;   // output col tile
  const int b  = blockIdx.z;
  const int t  = threadIdx.x;

  // ---- stage row-block (side 0) and col-block (side 1) as hi/lo bf16 ----
  // thread t handles row r = t>>1, k-half h = t&1 (32 floats)
  {
    const int r = t >> 1;
    const int h = t & 1;
    #pragma unroll
    for (int side = 0; side < 2; ++side) {
      const int tbase = (side == 0 ? bi : bj) * BT;
      unsigned char* dh = lds + (side == 0 ? OFF_RH : OFF_CH);
      unsigned char* dl = lds + (side == 0 ? OFF_RL : OFF_CL);
      const int g = tbase + r;
      float f[32];
      if (g < MM) {
        const float* src = (g < NSP)
            ? sp + ((size_t)b * NSP + g) * DD + h * 32
            : tm + ((size_t)b * NTM + (g - NSP)) * DD + h * 32;
        const float4* s4 = reinterpret_cast<const float4*>(src);
        #pragma unroll
        for (int i = 0; i < 8; ++i) {
          float4 v = s4[i];
          f[4*i+0] = v.x; f[4*i+1] = v.y; f[4*i+2] = v.z; f[4*i+3] = v.w;
        }
      } else {
        #pragma unroll
        for (int i = 0; i < 32; ++i) f[i] = 0.f;
      }
      #pragma unroll
      for (int c = 0; c < 4; ++c) {
        ushort8 H, L;
        #pragma unroll
        for (int i = 0; i < 8; ++i) {
          const float x = f[8*c + i];
          const unsigned short hi = bf16_rn(x);
          H[i] = (unsigned short)hi;
          L[i] = bf16_rn(x - bf16_f32(hi));
        }
        const unsigned slot = (unsigned)(h * 4 + c);
        const unsigned byte = (unsigned)(r << 7) + ((slot << 4) ^ (((unsigned)(r & 7)) << 4));
        *reinterpret_cast<ushort8*>(dh + byte) = H;
        *reinterpret_cast<ushort8*>(dl + byte) = L;
      }
    }
  }
  __syncthreads();

  // ---- compute: each wave (2x2) owns a 64x64 sub-tile = 4x4 MFMA tiles ----
  const int lane = t & 63;
  const int wave = t >> 6;
  const int wr = (wave >> 1) << 6;
  const int wc = (wave & 1) << 6;
  const int lr = lane & 15;
  const int lg = lane >> 4;

  f32x4 acc[4][4];
  #pragma unroll
  for (int m = 0; m < 4; ++m)
    #pragma unroll
    for (int n = 0; n < 4; ++n)
      acc[m][n] = (f32x4){0.f, 0.f, 0.f, 0.f};

  #pragma unroll
  for (int ks = 0; ks < 2; ++ks) {
    short8 ah[4], al[4], bh[4], bl[4];
    #pragma unroll
    for (int m = 0; m < 4; ++m) {
      const int rowa = wr + m * 16 + lr;
      const unsigned sa = ((unsigned)(lg + ks * 4)) << 4;
      const unsigned ba = (unsigned)(rowa << 7) + (sa ^ (((unsigned)(rowa & 7)) << 4));
      ah[m] = *reinterpret_cast<short8*>(lds + OFF_RH + ba);
      al[m] = *reinterpret_cast<short8*>(lds + OFF_RL + ba);
      const int rowb = wc + m * 16 + lr;
      const unsigned bb = (unsigned)(rowb << 7) + (sa ^ (((unsigned)(rowb & 7)) << 4));
      bh[m] = *reinterpret_cast<short8*>(lds + OFF_CH + bb);
      bl[m] = *reinterpret_cast<short8*>(lds + OFF_CL + bb);
    }
    #pragma unroll
    for (int m = 0; m < 4; ++m) {
      #pragma unroll
      for (int n = 0; n < 4; ++n) {
        acc[m][n] = __builtin_amdgcn_mfma_f32_16x16x32_bf16(ah[m], bh[n], acc[m][n], 0, 0, 0);
        acc[m][n] = __builtin_amdgcn_mfma_f32_16x16x32_bf16(ah[m], bl[n], acc[m][n], 0, 0, 0);
        acc[m][n] = __builtin_amdgcn_mfma_f32_16x16x32_bf16(al[m], bh[n], acc[m][n], 0, 0, 0);
      }
    }
  }

  // ---- epilogue: tanh(relu(x) + eye), guarded stores ----
  const size_t cbase = (size_t)b * MM * MM;
  const int gr0 = bi * BT + wr;
  const int gc0 = bj * BT + wc;
  #pragma unroll
  for (int m = 0; m < 4; ++m) {
    #pragma unroll
    for (int n = 0; n < 4; ++n) {
      const int gc = gc0 + n * 16 + lr;
      #pragma unroll
      for (int q = 0; q < 4; ++q) {
        const int gr = gr0 + m * 16 + lg * 4 + q;
        if (gr < MM && gc < MM) {
          float x = acc[m][n][q];
          x = fmaxf(x, 0.f);
          if (gr == gc) x += 1.f;
          // tanh(x) for x>=0: 1 - 2/(exp(2x)+1); exp2-based, saturates to 1.
          const float e = __builtin_amdgcn_exp2f(x * 2.8853900817779268f);
          out[cbase + (size_t)gr * MM + gc] = 1.f - 2.f * __builtin_amdgcn_rcpf(e + 1.f);
        }
      }
    }
  }
}

extern "C" void kernel_launch(void* const* d_in, const int* in_sizes, int n_in,
                              void* d_out, int out_size, void* d_ws, size_t ws_size,
                              hipStream_t stream) {
  const float* sp = (const float*)d_in[0];
  const float* tm = (const float*)d_in[1];
  float* out = (float*)d_out;
  const int B = in_sizes[0] / (NSP * DD);   // = 4
  dim3 grid(NTILE, NTILE, B);
  stg_adj_kernel<<<grid, dim3(256), 0, stream>>>(sp, tm, out);
}